// Round 18
// baseline (783.441 us; speedup 1.0000x reference)
//
#include <hip/hip_runtime.h>

// Problem constants
#define ND 128
#define NH 8
#define DHD 16

// ---------------------------------------------------------------------------
// Tiny kernel: per-head column sums of W_pd / W_pm and bias sums.
// ---------------------------------------------------------------------------
__global__ void k_wsum(const float* __restrict__ Wpd, const float* __restrict__ bpd,
                       const float* __restrict__ Wpm, const float* __restrict__ bpm,
                       float* __restrict__ wpd, float* __restrict__ wpm,
                       float* __restrict__ bs) {
  int t = blockIdx.x * blockDim.x + threadIdx.x;
  if (t < 1024) {
    int k = t >> 3, h = t & 7;
    float s = 0.f;
#pragma unroll
    for (int d = 0; d < 16; ++d) s += Wpd[k * 128 + h * 16 + d];
    wpd[t] = s;
  } else if (t < 2048) {
    int u = t - 1024, k = u >> 3, h = u & 7;
    float s = 0.f;
#pragma unroll
    for (int d = 0; d < 16; ++d) s += Wpm[k * 128 + h * 16 + d];
    wpm[u] = s;
  } else if (t < 2056) {
    int h = t - 2048;
    float s = 0.f;
#pragma unroll
    for (int d = 0; d < 16; ++d) s += bpd[h * 16 + d] + bpm[h * 16 + d];
    bs[h] = s;
  }
}

// ---------------------------------------------------------------------------
// MEGA kernel: esum blocks process TWO 32-edge tiles with register prefetch
// (tile i+1's global loads in flight during tile i's compute) — T14-style
// async-stage split. qkv blocks unchanged (8x4 tile). Bresenham interleave.
// ---------------------------------------------------------------------------
__global__ __launch_bounds__(256) void k_mega(
    const float* __restrict__ de, const float* __restrict__ m,
    const float* __restrict__ wpd, const float* __restrict__ wpm,
    const float* __restrict__ bs, const int* __restrict__ dst,
    int* __restrict__ counts, float* __restrict__ esum, int E_,
    int nQkv, int total,
    const float* __restrict__ X,
    const float* __restrict__ WQ, const float* __restrict__ bQ,
    const float* __restrict__ WK, const float* __restrict__ bK,
    const float* __restrict__ WV, const float* __restrict__ bV,
    float* __restrict__ Q, float* __restrict__ KV, int n) {
  __shared__ __align__(16) float smem[12352];   // 49408 B
  const int t = threadIdx.x;
  const long long b = blockIdx.x;
  const int fb  = (int)((b * (long long)nQkv) / total);
  const int fb1 = (int)(((b + 1) * (long long)nQkv) / total);
  if (fb1 == fb) {
    // ------------- esum body: 2 tiles, register-prefetched staging -------------
    const int ebid = (int)b - fb;
    float* sde = smem;                 // 32*129
    float* smm = sde + 32 * 129;       // 32*129
    float* swd = smm + 32 * 129;       // 1024
    float* swm = swd + 1024;           // 1024
    float* part = swm + 1024;          // 8*32*8
    for (int i = t; i < 1024; i += 256) { swd[i] = wpd[i]; swm[i] = wpm[i]; }
    const int baseE = ebid * 64;
    float4 vd[4], vm[4];
    // prefetch tile 0
    {
      const int e0 = baseE;
      const int nr = min(32, max(0, E_ - e0));
#pragma unroll
      for (int j = 0; j < 4; ++j) {
        const int f = t + j * 256;
        const int r = f >> 5, c = (f & 31) << 2;
        vd[j] = make_float4(0.f, 0.f, 0.f, 0.f);
        vm[j] = vd[j];
        if (r < nr) {
          vd[j] = *(const float4*)(de + (size_t)(e0 + r) * 128 + c);
          vm[j] = *(const float4*)(m + (size_t)(e0 + r) * 128 + c);
        }
      }
    }
    // write tile 0 to LDS
#pragma unroll
    for (int j = 0; j < 4; ++j) {
      const int f = t + j * 256;
      const int r = f >> 5, c = (f & 31) << 2;
      float* pd = &sde[r * 129 + c];
      pd[0] = vd[j].x; pd[1] = vd[j].y; pd[2] = vd[j].z; pd[3] = vd[j].w;
      float* pm2 = &smm[r * 129 + c];
      pm2[0] = vm[j].x; pm2[1] = vm[j].y; pm2[2] = vm[j].z; pm2[3] = vm[j].w;
    }
    __syncthreads();
#pragma unroll
    for (int tile = 0; tile < 2; ++tile) {
      const int e0 = baseE + tile * 32;
      const int nr = min(32, max(0, E_ - e0));
      // prefetch next tile (loads stay in flight through the compute below)
      if (tile == 0) {
        const int e1 = baseE + 32;
        const int nr1 = min(32, max(0, E_ - e1));
#pragma unroll
        for (int j = 0; j < 4; ++j) {
          const int f = t + j * 256;
          const int r = f >> 5, c = (f & 31) << 2;
          vd[j] = make_float4(0.f, 0.f, 0.f, 0.f);
          vm[j] = vd[j];
          if (r < nr1) {
            vd[j] = *(const float4*)(de + (size_t)(e1 + r) * 128 + c);
            vm[j] = *(const float4*)(m + (size_t)(e1 + r) * 128 + c);
          }
        }
      }
      // compute
      const int el = t & 31, kc = t >> 5;
      float acc[8];
#pragma unroll
      for (int h = 0; h < 8; ++h) acc[h] = 0.f;
      const int kbase = kc << 4;
#pragma unroll
      for (int j = 0; j < 16; ++j) {
        const int k = kbase + j;
        const float d = sde[el * 129 + k];
        const float mm = smm[el * 129 + k];
        const float4 w0 = *(const float4*)&swd[k * 8];
        const float4 w1 = *(const float4*)&swd[k * 8 + 4];
        const float4 x0 = *(const float4*)&swm[k * 8];
        const float4 x1 = *(const float4*)&swm[k * 8 + 4];
        acc[0] += d * w0.x + mm * x0.x;
        acc[1] += d * w0.y + mm * x0.y;
        acc[2] += d * w0.z + mm * x0.z;
        acc[3] += d * w0.w + mm * x0.w;
        acc[4] += d * w1.x + mm * x1.x;
        acc[5] += d * w1.y + mm * x1.y;
        acc[6] += d * w1.z + mm * x1.z;
        acc[7] += d * w1.w + mm * x1.w;
      }
      *(float4*)&part[(kc * 32 + el) * 8 + 0] = make_float4(acc[0], acc[1], acc[2], acc[3]);
      *(float4*)&part[(kc * 32 + el) * 8 + 4] = make_float4(acc[4], acc[5], acc[6], acc[7]);
      __syncthreads();   // compute reads of sde/smm complete; part visible
      const int el2 = t >> 3, h = t & 7;
      float s = bs[h];
#pragma unroll
      for (int kk = 0; kk < 8; ++kk) s += part[(kk * 32 + el2) * 8 + h];
      if (el2 < nr) esum[(size_t)(e0 + el2) * 8 + h] = s;
      if (t < nr) atomicAdd(&counts[dst[e0 + t]], 1);
      if (tile == 0) {
        // write prefetched tile 1 into LDS (safe: compute reads done)
#pragma unroll
        for (int j = 0; j < 4; ++j) {
          const int f = t + j * 256;
          const int r = f >> 5, c = (f & 31) << 2;
          float* pd = &sde[r * 129 + c];
          pd[0] = vd[j].x; pd[1] = vd[j].y; pd[2] = vd[j].z; pd[3] = vd[j].w;
          float* pm2 = &smm[r * 129 + c];
          pm2[0] = vm[j].x; pm2[1] = vm[j].y; pm2[2] = vm[j].z; pm2[3] = vm[j].w;
        }
        __syncthreads();
      }
    }
  } else {
    // ------------- qkv body (8x4 register tile) -------------
    float* xs = smem;  // [64][132]
    const int qbid = fb;
    const int mat = qbid % 3;
    const int r0 = (qbid / 3) * 64;
    const int tx = t & 31, ty = t >> 5;
    const float* __restrict__ W = (mat == 0) ? WQ : (mat == 1) ? WK : WV;
    const float* __restrict__ B = (mat == 0) ? bQ : (mat == 1) ? bK : bV;
    for (int i = t; i < 64 * 32; i += 256) {
      const int row = i >> 5, c4 = (i & 31) << 2;
      float4 v = make_float4(0.f, 0.f, 0.f, 0.f);
      if (r0 + row < n) v = *(const float4*)(X + (size_t)(r0 + row) * 128 + c4);
      *(float4*)&xs[row * 132 + c4] = v;
    }
    __syncthreads();
    float4 acc[8];
#pragma unroll
    for (int i = 0; i < 8; ++i) acc[i] = make_float4(0.f, 0.f, 0.f, 0.f);
    const int ty8 = ty << 3;
    const int cb = tx << 2;
#pragma unroll 4
    for (int k = 0; k < 128; ++k) {
      const float4 wv = *(const float4*)(W + (size_t)k * 128 + cb);
#pragma unroll
      for (int i = 0; i < 8; ++i) {
        const float x = xs[(ty8 + i) * 132 + k];
        acc[i].x += x * wv.x; acc[i].y += x * wv.y;
        acc[i].z += x * wv.z; acc[i].w += x * wv.w;
      }
    }
    const float4 bv = *(const float4*)(B + cb);
    float* __restrict__ Yp = (mat == 0) ? Q : KV;
    const int strideY = (mat == 0) ? 128 : 256;
    const int coff = ((mat == 2) ? 128 : 0) + cb;
#pragma unroll
    for (int i = 0; i < 8; ++i) {
      const int row = r0 + ty8 + i;
      if (row < n) {
        float4 o;
        o.x = acc[i].x + bv.x; o.y = acc[i].y + bv.y;
        o.z = acc[i].z + bv.z; o.w = acc[i].w + bv.w;
        *(float4*)(Yp + (size_t)row * strideY + coff) = o;
      }
    }
  }
}

// ---------------------------------------------------------------------------
// CSR build: scan + scatter.
// ---------------------------------------------------------------------------
__global__ __launch_bounds__(1024) void k_scan(const int* __restrict__ counts,
                                               int* __restrict__ rs,
                                               int* __restrict__ cursor, int N_) {
  __shared__ int ls[1024];
  const int t = threadIdx.x;
  const int CH = (N_ + 1023) >> 10;
  const int b0 = t * CH, b1 = min(N_, b0 + CH);
  int s = 0;
  for (int i = b0; i < b1; ++i) s += counts[i];
  ls[t] = s;
  __syncthreads();
  for (int off = 1; off < 1024; off <<= 1) {
    int v = (t >= off) ? ls[t - off] : 0;
    __syncthreads();
    ls[t] += v;
    __syncthreads();
  }
  int run = ls[t] - s;
  for (int i = b0; i < b1; ++i) {
    rs[i] = run;
    cursor[i] = run;
    run += counts[i];
  }
  if (t == 1023) rs[N_] = ls[1023];
}

__global__ __launch_bounds__(256) void k_scatter2(const int* __restrict__ src,
                                                  const int* __restrict__ dst,
                                                  int* __restrict__ cursor,
                                                  const float4* __restrict__ esum_in,
                                                  int* __restrict__ eidxs,
                                                  float4* __restrict__ esum_csr, int E_) {
  const int i = blockIdx.x * blockDim.x + threadIdx.x;
  const int n = gridDim.x * blockDim.x;
  for (int e = i; e < E_; e += n) {
    const int d = dst[e];
    const int p = atomicAdd(&cursor[d], 1);
    eidxs[p] = src[e];
    const float4 a = esum_in[2 * (size_t)e];
    const float4 b = esum_in[2 * (size_t)e + 1];
    esum_csr[2 * (size_t)p] = a;
    esum_csr[2 * (size_t)p + 1] = b;
  }
}

// ---------------------------------------------------------------------------
// Gather-side attention: one wave per dst node, head-per-lane layout,
// 16 edges in flight. esum CSR-ordered; src-only edge list.
// ---------------------------------------------------------------------------
__global__ __launch_bounds__(256) void k_node_attn(const float* __restrict__ Q,
                                                   const float* __restrict__ KV,
                                                   const float* __restrict__ esum_csr,
                                                   const int* __restrict__ rs,
                                                   const int* __restrict__ eidxs,
                                                   float* __restrict__ wV,
                                                   float* __restrict__ z, int n) {
  const int node = (blockIdx.x * blockDim.x + threadIdx.x) >> 6;
  if (node >= n) return;
  const int lane = threadIdx.x & 63;
  const int g = lane >> 3;
  const int l = lane & 7;
  const int d0 = l << 4;
  const float* qp = Q + (size_t)node * 128 + d0;
  const float4 q0 = *(const float4*)(qp);
  const float4 q1 = *(const float4*)(qp + 4);
  const float4 q2 = *(const float4*)(qp + 8);
  const float4 q3 = *(const float4*)(qp + 12);
  float4 a0 = make_float4(0.f, 0.f, 0.f, 0.f);
  float4 a1 = a0, a2 = a0, a3 = a0;
  float zacc = 0.f;
  const int start = rs[node], end = rs[node + 1];
  for (int base = start; base < end; base += 16) {
    const bool p0 = base + g < end;
    const bool p1 = base + 8 + g < end;
    const int i0 = min(base + g, end - 1);
    const int i1 = min(base + 8 + g, end - 1);
    const int sn0 = eidxs[i0];
    const int sn1 = eidxs[i1];
    const float* kp0 = KV + (size_t)sn0 * 256 + d0;
    const float* kp1 = KV + (size_t)sn1 * 256 + d0;
    const float es0 = esum_csr[(size_t)i0 * 8 + l];
    const float es1 = esum_csr[(size_t)i1 * 8 + l];
    float4 k0, k1, k2, k3;
    k0 = *(const float4*)(kp0);
    k1 = *(const float4*)(kp0 + 4);
    k2 = *(const float4*)(kp0 + 8);
    k3 = *(const float4*)(kp0 + 12);
    float qkA = q0.x * k0.x + q0.y * k0.y + q0.z * k0.z + q0.w * k0.w
              + q1.x * k1.x + q1.y * k1.y + q1.z * k1.z + q1.w * k1.w
              + q2.x * k2.x + q2.y * k2.y + q2.z * k2.z + q2.w * k2.w
              + q3.x * k3.x + q3.y * k3.y + q3.z * k3.z + q3.w * k3.w;
    k0 = *(const float4*)(kp1);
    k1 = *(const float4*)(kp1 + 4);
    k2 = *(const float4*)(kp1 + 8);
    k3 = *(const float4*)(kp1 + 12);
    float qkB = q0.x * k0.x + q0.y * k0.y + q0.z * k0.z + q0.w * k0.w
              + q1.x * k1.x + q1.y * k1.y + q1.z * k1.z + q1.w * k1.w
              + q2.x * k2.x + q2.y * k2.y + q2.z * k2.z + q2.w * k2.w
              + q3.x * k3.x + q3.y * k3.y + q3.z * k3.z + q3.w * k3.w;
    float s0 = __expf(fminf(5.f, fmaxf(-5.f, 4.f * qkA + es0)));
    float s1 = __expf(fminf(5.f, fmaxf(-5.f, 4.f * qkB + es1)));
    s0 = p0 ? s0 : 0.f;
    s1 = p1 ? s1 : 0.f;
    {
      const float* vp = kp0 + 128;
      const float4 v0 = *(const float4*)(vp);
      const float4 v1 = *(const float4*)(vp + 4);
      const float4 v2 = *(const float4*)(vp + 8);
      const float4 v3 = *(const float4*)(vp + 12);
      a0.x += v0.x * s0; a0.y += v0.y * s0; a0.z += v0.z * s0; a0.w += v0.w * s0;
      a1.x += v1.x * s0; a1.y += v1.y * s0; a1.z += v1.z * s0; a1.w += v1.w * s0;
      a2.x += v2.x * s0; a2.y += v2.y * s0; a2.z += v2.z * s0; a2.w += v2.w * s0;
      a3.x += v3.x * s0; a3.y += v3.y * s0; a3.z += v3.z * s0; a3.w += v3.w * s0;
    }
    {
      const float* vp = kp1 + 128;
      const float4 v0 = *(const float4*)(vp);
      const float4 v1 = *(const float4*)(vp + 4);
      const float4 v2 = *(const float4*)(vp + 8);
      const float4 v3 = *(const float4*)(vp + 12);
      a0.x += v0.x * s1; a0.y += v0.y * s1; a0.z += v0.z * s1; a0.w += v0.w * s1;
      a1.x += v1.x * s1; a1.y += v1.y * s1; a1.z += v1.z * s1; a1.w += v1.w * s1;
      a2.x += v2.x * s1; a2.y += v2.y * s1; a2.z += v2.z * s1; a2.w += v2.w * s1;
      a3.x += v3.x * s1; a3.y += v3.y * s1; a3.z += v3.z * s1; a3.w += v3.w * s1;
    }
    zacc += s0 + s1;
  }
#pragma unroll
  for (int st = 8; st < 64; st <<= 1) {
    a0.x += __shfl_xor(a0.x, st); a0.y += __shfl_xor(a0.y, st);
    a0.z += __shfl_xor(a0.z, st); a0.w += __shfl_xor(a0.w, st);
    a1.x += __shfl_xor(a1.x, st); a1.y += __shfl_xor(a1.y, st);
    a1.z += __shfl_xor(a1.z, st); a1.w += __shfl_xor(a1.w, st);
    a2.x += __shfl_xor(a2.x, st); a2.y += __shfl_xor(a2.y, st);
    a2.z += __shfl_xor(a2.z, st); a2.w += __shfl_xor(a2.w, st);
    a3.x += __shfl_xor(a3.x, st); a3.y += __shfl_xor(a3.y, st);
    a3.z += __shfl_xor(a3.z, st); a3.w += __shfl_xor(a3.w, st);
    zacc += __shfl_xor(zacc, st);
  }
  if (g < 4) {
    float4 w = a0;
    if (g == 1) w = a1;
    if (g == 2) w = a2;
    if (g == 3) w = a3;
    *(float4*)(wV + (size_t)node * 128 + d0 + (g << 2)) = w;
  }
  if (g == 0) z[(size_t)node * 8 + l] = zacc;
}

// ---------------------------------------------------------------------------
// Fused: attn normalize + I@W_i + b_i -> T (LDS) -> @W_O + b_O + residual(h)
// + LN1 + BN1 -> h2. 64 rows/block, 8x4 register tiles.  (R16-exact)
// ---------------------------------------------------------------------------
__global__ __launch_bounds__(256) void k_attnln(const float* __restrict__ I_,
                                                const float* __restrict__ Wi,
                                                const float* __restrict__ bi,
                                                const float* __restrict__ wV,
                                                const float* __restrict__ z,
                                                const float* __restrict__ WO,
                                                const float* __restrict__ bO,
                                                const float* __restrict__ RES,
                                                const float* __restrict__ lng,
                                                const float* __restrict__ lnb,
                                                const float* __restrict__ bng,
                                                const float* __restrict__ bnb,
                                                float* __restrict__ Y, int n) {
  __shared__ float xs[64][132];
  __shared__ float is[64][68];
  const int t = threadIdx.x;
  const int tx = t & 31, ty = t >> 5;
  const int r0 = blockIdx.x * 64;
  const int cb = tx << 2;
  const int ty8 = ty << 3;
  for (int i = t; i < 64 * 16; i += 256) {
    const int row = i >> 4, c4 = (i & 15) << 2;
    float4 v = make_float4(0.f, 0.f, 0.f, 0.f);
    if (r0 + row < n) v = *(const float4*)(I_ + (size_t)(r0 + row) * 64 + c4);
    *(float4*)&is[row][c4] = v;
  }
  __syncthreads();
  {
    float4 acc[8];
#pragma unroll
    for (int i = 0; i < 8; ++i) acc[i] = make_float4(0.f, 0.f, 0.f, 0.f);
#pragma unroll 4
    for (int k = 0; k < 64; ++k) {
      const float4 wv = *(const float4*)(Wi + (size_t)k * 128 + cb);
#pragma unroll
      for (int i = 0; i < 8; ++i) {
        const float x = is[ty8 + i][k];
        acc[i].x += x * wv.x; acc[i].y += x * wv.y;
        acc[i].z += x * wv.z; acc[i].w += x * wv.w;
      }
    }
    const float4 bv = *(const float4*)(bi + cb);
    const int hh = cb >> 4;
#pragma unroll
    for (int i = 0; i < 8; ++i) {
      const int row = r0 + ty8 + i;
      float4 o = make_float4(0.f, 0.f, 0.f, 0.f);
      if (row < n) {
        const float rz = 1.f / (z[(size_t)row * 8 + hh] + 1e-10f);
        const float4 wv4 = *(const float4*)(wV + (size_t)row * 128 + cb);
        o.x = wv4.x * rz + acc[i].x + bv.x;
        o.y = wv4.y * rz + acc[i].y + bv.y;
        o.z = wv4.z * rz + acc[i].z + bv.z;
        o.w = wv4.w * rz + acc[i].w + bv.w;
      }
      *(float4*)&xs[ty8 + i][cb] = o;
    }
  }
  __syncthreads();
  float4 acc[8];
#pragma unroll
  for (int i = 0; i < 8; ++i) acc[i] = make_float4(0.f, 0.f, 0.f, 0.f);
#pragma unroll 4
  for (int k = 0; k < 128; ++k) {
    const float4 wv = *(const float4*)(WO + (size_t)k * 128 + cb);
#pragma unroll
    for (int i = 0; i < 8; ++i) {
      const float x = xs[ty8 + i][k];
      acc[i].x += x * wv.x; acc[i].y += x * wv.y;
      acc[i].z += x * wv.z; acc[i].w += x * wv.w;
    }
  }
  const float4 bv  = *(const float4*)(bO + cb);
  const float4 g4  = *(const float4*)(lng + cb);
  const float4 lb4 = *(const float4*)(lnb + cb);
  const float bnscale = rsqrtf(1.f + 1e-5f);
  float4 bg4 = *(const float4*)(bng + cb);
  bg4.x *= bnscale; bg4.y *= bnscale; bg4.z *= bnscale; bg4.w *= bnscale;
  const float4 bb4 = *(const float4*)(bnb + cb);
#pragma unroll
  for (int i = 0; i < 8; ++i) {
    const int row = r0 + ty8 + i;
    float4 v = acc[i];
    v.x += bv.x; v.y += bv.y; v.z += bv.z; v.w += bv.w;
    if (row < n) {
      const float4 rr = *(const float4*)(RES + (size_t)row * 128 + cb);
      v.x += rr.x; v.y += rr.y; v.z += rr.z; v.w += rr.w;
    }
    float s1 = v.x + v.y + v.z + v.w;
    float s2 = v.x * v.x + v.y * v.y + v.z * v.z + v.w * v.w;
#pragma unroll
    for (int st = 1; st < 32; st <<= 1) {
      s1 += __shfl_xor(s1, st);
      s2 += __shfl_xor(s2, st);
    }
    const float mu = s1 * (1.f / 128.f);
    const float var = s2 * (1.f / 128.f) - mu * mu;
    const float rsg = rsqrtf(var + 1e-5f);
    if (row < n) {
      float4 o;
      o.x = ((v.x - mu) * rsg * g4.x + lb4.x) * bg4.x + bb4.x;
      o.y = ((v.y - mu) * rsg * g4.y + lb4.y) * bg4.y + bb4.y;
      o.z = ((v.z - mu) * rsg * g4.z + lb4.z) * bg4.z + bb4.z;
      o.w = ((v.w - mu) * rsg * g4.w + lb4.w) * bg4.w + bb4.w;
      *(float4*)(Y + (size_t)row * 128 + cb) = o;
    }
  }
}

// ---------------------------------------------------------------------------
// 8x4 register-tiled GEMM + bias (+ReLU). (R16-exact)
// ---------------------------------------------------------------------------
template <int CI, int CO, bool RELU>
__global__ __launch_bounds__(256) void k_gemm8(const float* __restrict__ X,
                                               const float* __restrict__ W,
                                               const float* __restrict__ B,
                                               float* __restrict__ Y, int n) {
  __shared__ float xs[64][CI + 4];
  const int t = threadIdx.x;
  const int tx = t & 31, ty = t >> 5;
  const int r0 = blockIdx.x * 64;
  const int c0 = blockIdx.y * 128;
  for (int i = t; i < 64 * (CI / 4); i += 256) {
    const int row = i / (CI / 4);
    const int c4 = (i % (CI / 4)) << 2;
    float4 v = make_float4(0.f, 0.f, 0.f, 0.f);
    if (r0 + row < n) v = *(const float4*)(X + (size_t)(r0 + row) * CI + c4);
    *(float4*)&xs[row][c4] = v;
  }
  __syncthreads();
  float4 acc[8];
#pragma unroll
  for (int i = 0; i < 8; ++i) acc[i] = make_float4(0.f, 0.f, 0.f, 0.f);
  const int ty8 = ty << 3;
  const int cb = c0 + (tx << 2);
#pragma unroll 4
  for (int k = 0; k < CI; ++k) {
    const float4 wv = *(const float4*)(W + (size_t)k * CO + cb);
#pragma unroll
    for (int i = 0; i < 8; ++i) {
      const float x = xs[ty8 + i][k];
      acc[i].x += x * wv.x; acc[i].y += x * wv.y;
      acc[i].z += x * wv.z; acc[i].w += x * wv.w;
    }
  }
  const float4 bv = *(const float4*)(B + cb);
#pragma unroll
  for (int i = 0; i < 8; ++i) {
    const int row = r0 + ty8 + i;
    if (row < n) {
      float4 o;
      o.x = acc[i].x + bv.x; o.y = acc[i].y + bv.y;
      o.z = acc[i].z + bv.z; o.w = acc[i].w + bv.w;
      if (RELU) {
        o.x = fmaxf(o.x, 0.f); o.y = fmaxf(o.y, 0.f);
        o.z = fmaxf(o.z, 0.f); o.w = fmaxf(o.w, 0.f);
      }
      *(float4*)(Y + (size_t)row * CO + c0 + (tx << 2)) = o;
    }
  }
}

// ---------------------------------------------------------------------------
// 8x4 register-tiled GEMM (CI->128) + bias + residual + LN + BN. (R16-exact)
// ---------------------------------------------------------------------------
template <int CI>
__global__ __launch_bounds__(256) void k_gemm8ln(const float* __restrict__ X,
                                                 const float* __restrict__ W,
                                                 const float* __restrict__ B,
                                                 const float* __restrict__ RES,
                                                 const float* __restrict__ lng,
                                                 const float* __restrict__ lnb,
                                                 const float* __restrict__ bng,
                                                 const float* __restrict__ bnb,
                                                 float* __restrict__ Y, int n) {
  __shared__ float xs[64][132];
  const int t = threadIdx.x;
  const int tx = t & 31, ty = t >> 5;
  const int r0 = blockIdx.x * 64;
  const int cb = tx << 2;
  float4 acc[8];
#pragma unroll
  for (int i = 0; i < 8; ++i) acc[i] = make_float4(0.f, 0.f, 0.f, 0.f);
  const int ty8 = ty << 3;
  for (int kb = 0; kb < CI; kb += 128) {
    for (int i = t; i < 64 * 32; i += 256) {
      const int row = i >> 5, c4 = (i & 31) << 2;
      float4 v = make_float4(0.f, 0.f, 0.f, 0.f);
      if (r0 + row < n) v = *(const float4*)(X + (size_t)(r0 + row) * CI + kb + c4);
      *(float4*)&xs[row][c4] = v;
    }
    __syncthreads();
#pragma unroll 4
    for (int k = 0; k < 128; ++k) {
      const float4 wv = *(const float4*)(W + (size_t)(kb + k) * 128 + cb);
#pragma unroll
      for (int i = 0; i < 8; ++i) {
        const float x = xs[ty8 + i][k];
        acc[i].x += x * wv.x; acc[i].y += x * wv.y;
        acc[i].z += x * wv.z; acc[i].w += x * wv.w;
      }
    }
    __syncthreads();
  }
  const float4 bv  = *(const float4*)(B + cb);
  const float4 g4  = *(const float4*)(lng + cb);
  const float4 lb4 = *(const float4*)(lnb + cb);
  const float bnscale = rsqrtf(1.f + 1e-5f);
  float4 bg4 = *(const float4*)(bng + cb);
  bg4.x *= bnscale; bg4.y *= bnscale; bg4.z *= bnscale; bg4.w *= bnscale;
  const float4 bb4 = *(const float4*)(bnb + cb);
#pragma unroll
  for (int i = 0; i < 8; ++i) {
    const int row = r0 + ty8 + i;
    float4 v = acc[i];
    v.x += bv.x; v.y += bv.y; v.z += bv.z; v.w += bv.w;
    if (row < n) {
      const float4 rr = *(const float4*)(RES + (size_t)row * 128 + cb);
      v.x += rr.x; v.y += rr.y; v.z += rr.z; v.w += rr.w;
    }
    float s1 = v.x + v.y + v.z + v.w;
    float s2 = v.x * v.x + v.y * v.y + v.z * v.z + v.w * v.w;
#pragma unroll
    for (int st = 1; st < 32; st <<= 1) {
      s1 += __shfl_xor(s1, st);
      s2 += __shfl_xor(s2, st);
    }
    const float mu = s1 * (1.f / 128.f);
    const float var = s2 * (1.f / 128.f) - mu * mu;
    const float rsg = rsqrtf(var + 1e-5f);
    if (row < n) {
      float4 o;
      o.x = ((v.x - mu) * rsg * g4.x + lb4.x) * bg4.x + bb4.x;
      o.y = ((v.y - mu) * rsg * g4.y + lb4.y) * bg4.y + bb4.y;
      o.z = ((v.z - mu) * rsg * g4.z + lb4.z) * bg4.z + bb4.z;
      o.w = ((v.w - mu) * rsg * g4.w + lb4.w) * bg4.w + bb4.w;
      *(float4*)(Y + (size_t)row * 128 + cb) = o;
    }
  }
}

// ---------------------------------------------------------------------------
extern "C" void kernel_launch(void* const* d_in, const int* in_sizes, int n_in,
                              void* d_out, int out_size, void* d_ws, size_t ws_size,
                              hipStream_t stream) {
  const float* h_   = (const float*)d_in[0];
  const float* de   = (const float*)d_in[1];
  const float* m_   = (const float*)d_in[2];
  const float* I_   = (const float*)d_in[3];
  const float* W_Q  = (const float*)d_in[4];
  const float* b_Q  = (const float*)d_in[5];
  const float* W_K  = (const float*)d_in[6];
  const float* b_K  = (const float*)d_in[7];
  const float* W_V  = (const float*)d_in[8];
  const float* b_V  = (const float*)d_in[9];
  const float* W_pd = (const float*)d_in[10];
  const float* b_pd = (const float*)d_in[11];
  const float* W_pm = (const float*)d_in[12];
  const float* b_pm = (const float*)d_in[13];
  const float* W_i  = (const float*)d_in[14];
  const float* b_i  = (const float*)d_in[15];
  const float* W_O  = (const float*)d_in[16];
  const float* b_O  = (const float*)d_in[17];
  const float* ln1g = (const float*)d_in[18];
  const float* ln1b = (const float*)d_in[19];
  const float* bn1g = (const float*)d_in[20];
  const float* bn1b = (const float*)d_in[21];
  const float* W_f1 = (const float*)d_in[22];
  const float* b_f1 = (const float*)d_in[23];
  const float* W_f2 = (const float*)d_in[24];
  const float* b_f2 = (const float*)d_in[25];
  const float* ln2g = (const float*)d_in[26];
  const float* ln2b = (const float*)d_in[27];
  const float* bn2g = (const float*)d_in[28];
  const float* bn2b = (const float*)d_in[29];
  const int* src    = (const int*)d_in[30];
  const int* dst    = (const int*)d_in[31];

  const int N_ = in_sizes[0] / 128;   // 50000
  const int E_ = in_sizes[30];        // 800000
  const size_t ND_ = (size_t)N_ * 128;

  float* ws = (float*)d_ws;
  size_t off = 0;
  float* Qb      = ws + off; off += ND_;
  float* KVb     = ws + off; off += (size_t)N_ * 256;
  float* wV      = ws + off; off += ND_;
  float* zb      = ws + off; off += (size_t)N_ * 8;
  float* esum    = ws + off; off += (size_t)E_ * 8;
  float* esumcsr = ws + off; off += (size_t)E_ * 8;
  float* h2      = ws + off; off += ND_;
  float* hid     = ws + off; off += (size_t)N_ * 256;
  float* wpd     = ws + off; off += 1024;
  float* wpm     = ws + off; off += 1024;
  float* bs      = ws + off; off += 8;
  (void)ws_size; (void)n_in; (void)out_size;

  // CSR arrays aliased into hid (dead until FFN stage)
  int* rs     = (int*)hid;
  int* cursor = rs + (N_ + 2);
  int* eidxs  = cursor + (N_ + 2);

  float* out = (float*)d_out;
  const int nrb64 = (N_ + 63) / 64;
  const int nEsum = (E_ + 63) / 64;   // 2 tiles per block
  const int nQkv = 3 * nrb64;
  const int total = nEsum + nQkv;

  // 1. weight head-sums; zero counts for fused histogram
  k_wsum<<<9, 256, 0, stream>>>(W_pd, b_pd, W_pm, b_pm, wpd, wpm, bs);
  hipMemsetAsync(cursor, 0, (size_t)N_ * sizeof(int), stream);

  // 2+3. MEGA: esum (2-tile pipelined, +histogram) || QKV
  k_mega<<<total, 256, 0, stream>>>(
      de, m_, wpd, wpm, bs, dst, cursor, esum, E_, nQkv, total,
      h_, W_Q, b_Q, W_K, b_K, W_V, b_V, Qb, KVb, N_);

  // 4. CSR: scan -> scatter (also permutes esum into CSR order)
  k_scan<<<1, 1024, 0, stream>>>(cursor, rs, cursor, N_);
  k_scatter2<<<1024, 256, 0, stream>>>(src, dst, cursor, (const float4*)esum,
                                       eidxs, (float4*)esumcsr, E_);

  // 5. gather-side attention
  k_node_attn<<<(N_ + 3) / 4, 256, 0, stream>>>(Qb, KVb, esumcsr, rs, eidxs, wV, zb, N_);

  // 6+7. fused: attn normalize + I@W_i -> T (LDS) -> W_O + residual + LN1 + BN1
  k_attnln<<<nrb64, 256, 0, stream>>>(I_, W_i, b_i, wV, zb, W_O, b_O, h_,
                                      ln1g, ln1b, bn1g, bn1b, h2, N_);

  // 8. FFN1 (ReLU), 8x4 tiles — overwrites CSR scratch (dead by now)
  k_gemm8<128, 256, true><<<dim3(nrb64, 2), 256, 0, stream>>>(h2, W_f1, b_f1, hid, N_);

  // 9. FFN2 + residual(h2) + LN2 + BN2 -> out (8x4 tiles, fused)
  k_gemm8ln<256><<<nrb64, 256, 0, stream>>>(hid, W_f2, b_f2, h2, ln2g, ln2b, bn2g, bn2b, out, N_);
}

// Round 19
// 760.289 us; speedup vs baseline: 1.0305x; 1.0305x over previous
//
#include <hip/hip_runtime.h>

// Problem constants
#define ND 128
#define NH 8
#define DHD 16

// ---------------------------------------------------------------------------
// Tiny kernel: per-head column sums of W_pd / W_pm and bias sums.
// ---------------------------------------------------------------------------
__global__ void k_wsum(const float* __restrict__ Wpd, const float* __restrict__ bpd,
                       const float* __restrict__ Wpm, const float* __restrict__ bpm,
                       float* __restrict__ wpd, float* __restrict__ wpm,
                       float* __restrict__ bs) {
  int t = blockIdx.x * blockDim.x + threadIdx.x;
  if (t < 1024) {
    int k = t >> 3, h = t & 7;
    float s = 0.f;
#pragma unroll
    for (int d = 0; d < 16; ++d) s += Wpd[k * 128 + h * 16 + d];
    wpd[t] = s;
  } else if (t < 2048) {
    int u = t - 1024, k = u >> 3, h = u & 7;
    float s = 0.f;
#pragma unroll
    for (int d = 0; d < 16; ++d) s += Wpm[k * 128 + h * 16 + d];
    wpm[u] = s;
  } else if (t < 2056) {
    int h = t - 2048;
    float s = 0.f;
#pragma unroll
    for (int d = 0; d < 16; ++d) s += bpd[h * 16 + d] + bpm[h * 16 + d];
    bs[h] = s;
  }
}

// ---------------------------------------------------------------------------
// MEGA kernel with Bresenham-interleaved block roles (esum || qkv). R16-exact.
// ---------------------------------------------------------------------------
__global__ __launch_bounds__(256) void k_mega(
    const float* __restrict__ de, const float* __restrict__ m,
    const float* __restrict__ wpd, const float* __restrict__ wpm,
    const float* __restrict__ bs, const int* __restrict__ dst,
    int* __restrict__ counts, float* __restrict__ esum, int E_,
    int nQkv, int total,
    const float* __restrict__ X,
    const float* __restrict__ WQ, const float* __restrict__ bQ,
    const float* __restrict__ WK, const float* __restrict__ bK,
    const float* __restrict__ WV, const float* __restrict__ bV,
    float* __restrict__ Q, float* __restrict__ KV, int n) {
  __shared__ __align__(16) float smem[12352];   // 49408 B
  const int t = threadIdx.x;
  const long long b = blockIdx.x;
  const int fb  = (int)((b * (long long)nQkv) / total);
  const int fb1 = (int)(((b + 1) * (long long)nQkv) / total);
  if (fb1 == fb) {
    // esum body (R7-exact)
    const int ebid = (int)b - fb;
    float* sde = smem;
    float* smm = sde + 32 * 129;
    float* swd = smm + 32 * 129;
    float* swm = swd + 1024;
    float* part = swm + 1024;
    for (int i = t; i < 1024; i += 256) { swd[i] = wpd[i]; swm[i] = wpm[i]; }
    const int e0 = ebid * 32;
    const int nr = min(32, E_ - e0);
    if (nr == 32) {
#pragma unroll
      for (int j = 0; j < 4; ++j) {
        const int f = t + j * 256;
        const int r = f >> 5, c = (f & 31) << 2;
        const float4 v = *(const float4*)(de + (size_t)(e0 + r) * 128 + c);
        const float4 w = *(const float4*)(m + (size_t)(e0 + r) * 128 + c);
        float* pd = &sde[r * 129 + c];
        pd[0] = v.x; pd[1] = v.y; pd[2] = v.z; pd[3] = v.w;
        float* pm2 = &smm[r * 129 + c];
        pm2[0] = w.x; pm2[1] = w.y; pm2[2] = w.z; pm2[3] = w.w;
      }
    } else {
#pragma unroll
      for (int j = 0; j < 4; ++j) {
        const int f = t + j * 256;
        const int r = f >> 5, c = (f & 31) << 2;
        float4 v = make_float4(0.f, 0.f, 0.f, 0.f), w = v;
        if (r < nr) {
          v = *(const float4*)(de + (size_t)(e0 + r) * 128 + c);
          w = *(const float4*)(m + (size_t)(e0 + r) * 128 + c);
        }
        float* pd = &sde[r * 129 + c];
        pd[0] = v.x; pd[1] = v.y; pd[2] = v.z; pd[3] = v.w;
        float* pm2 = &smm[r * 129 + c];
        pm2[0] = w.x; pm2[1] = w.y; pm2[2] = w.z; pm2[3] = w.w;
      }
    }
    __syncthreads();
    const int el = t & 31, kc = t >> 5;
    float acc[8];
#pragma unroll
    for (int h = 0; h < 8; ++h) acc[h] = 0.f;
    const int kbase = kc << 4;
#pragma unroll
    for (int j = 0; j < 16; ++j) {
      const int k = kbase + j;
      const float d = sde[el * 129 + k];
      const float mm = smm[el * 129 + k];
      const float4 w0 = *(const float4*)&swd[k * 8];
      const float4 w1 = *(const float4*)&swd[k * 8 + 4];
      const float4 x0 = *(const float4*)&swm[k * 8];
      const float4 x1 = *(const float4*)&swm[k * 8 + 4];
      acc[0] += d * w0.x + mm * x0.x;
      acc[1] += d * w0.y + mm * x0.y;
      acc[2] += d * w0.z + mm * x0.z;
      acc[3] += d * w0.w + mm * x0.w;
      acc[4] += d * w1.x + mm * x1.x;
      acc[5] += d * w1.y + mm * x1.y;
      acc[6] += d * w1.z + mm * x1.z;
      acc[7] += d * w1.w + mm * x1.w;
    }
    *(float4*)&part[(kc * 32 + el) * 8 + 0] = make_float4(acc[0], acc[1], acc[2], acc[3]);
    *(float4*)&part[(kc * 32 + el) * 8 + 4] = make_float4(acc[4], acc[5], acc[6], acc[7]);
    __syncthreads();
    const int el2 = t >> 3, h = t & 7;
    float s = bs[h];
#pragma unroll
    for (int kk = 0; kk < 8; ++kk) s += part[(kk * 32 + el2) * 8 + h];
    if (el2 < nr) esum[(size_t)(e0 + el2) * 8 + h] = s;
    if (t < nr) atomicAdd(&counts[dst[e0 + t]], 1);
  } else {
    // qkv body (8x4 register tile)
    float* xs = smem;  // [64][132]
    const int qbid = fb;
    const int mat = qbid % 3;
    const int r0 = (qbid / 3) * 64;
    const int tx = t & 31, ty = t >> 5;
    const float* __restrict__ W = (mat == 0) ? WQ : (mat == 1) ? WK : WV;
    const float* __restrict__ B = (mat == 0) ? bQ : (mat == 1) ? bK : bV;
    for (int i = t; i < 64 * 32; i += 256) {
      const int row = i >> 5, c4 = (i & 31) << 2;
      float4 v = make_float4(0.f, 0.f, 0.f, 0.f);
      if (r0 + row < n) v = *(const float4*)(X + (size_t)(r0 + row) * 128 + c4);
      *(float4*)&xs[row * 132 + c4] = v;
    }
    __syncthreads();
    float4 acc[8];
#pragma unroll
    for (int i = 0; i < 8; ++i) acc[i] = make_float4(0.f, 0.f, 0.f, 0.f);
    const int ty8 = ty << 3;
    const int cb = tx << 2;
#pragma unroll 4
    for (int k = 0; k < 128; ++k) {
      const float4 wv = *(const float4*)(W + (size_t)k * 128 + cb);
#pragma unroll
      for (int i = 0; i < 8; ++i) {
        const float x = xs[(ty8 + i) * 132 + k];
        acc[i].x += x * wv.x; acc[i].y += x * wv.y;
        acc[i].z += x * wv.z; acc[i].w += x * wv.w;
      }
    }
    const float4 bv = *(const float4*)(B + cb);
    float* __restrict__ Yp = (mat == 0) ? Q : KV;
    const int strideY = (mat == 0) ? 128 : 256;
    const int coff = ((mat == 2) ? 128 : 0) + cb;
#pragma unroll
    for (int i = 0; i < 8; ++i) {
      const int row = r0 + ty8 + i;
      if (row < n) {
        float4 o;
        o.x = acc[i].x + bv.x; o.y = acc[i].y + bv.y;
        o.z = acc[i].z + bv.z; o.w = acc[i].w + bv.w;
        *(float4*)(Yp + (size_t)row * strideY + coff) = o;
      }
    }
  }
}

// ---------------------------------------------------------------------------
// CSR build: scan + scatter (hist fused into mega/esum).
// ---------------------------------------------------------------------------
__global__ __launch_bounds__(1024) void k_scan(const int* __restrict__ counts,
                                               int* __restrict__ rs,
                                               int* __restrict__ cursor, int N_) {
  __shared__ int ls[1024];
  const int t = threadIdx.x;
  const int CH = (N_ + 1023) >> 10;
  const int b0 = t * CH, b1 = min(N_, b0 + CH);
  int s = 0;
  for (int i = b0; i < b1; ++i) s += counts[i];
  ls[t] = s;
  __syncthreads();
  for (int off = 1; off < 1024; off <<= 1) {
    int v = (t >= off) ? ls[t - off] : 0;
    __syncthreads();
    ls[t] += v;
    __syncthreads();
  }
  int run = ls[t] - s;
  for (int i = b0; i < b1; ++i) {
    rs[i] = run;
    cursor[i] = run;
    run += counts[i];
  }
  if (t == 1023) rs[N_] = ls[1023];
}

__global__ __launch_bounds__(256) void k_scatter2(const int* __restrict__ src,
                                                  const int* __restrict__ dst,
                                                  int* __restrict__ cursor,
                                                  const float4* __restrict__ esum_in,
                                                  int* __restrict__ eidxs,
                                                  float4* __restrict__ esum_csr, int E_) {
  const int i = blockIdx.x * blockDim.x + threadIdx.x;
  const int n = gridDim.x * blockDim.x;
  for (int e = i; e < E_; e += n) {
    const int d = dst[e];
    const int p = atomicAdd(&cursor[d], 1);
    eidxs[p] = src[e];
    const float4 a = esum_in[2 * (size_t)e];
    const float4 b = esum_in[2 * (size_t)e + 1];
    esum_csr[2 * (size_t)p] = a;
    esum_csr[2 * (size_t)p + 1] = b;
  }
}

// ---------------------------------------------------------------------------
// Gather-side attention: one wave per dst node, head-per-lane layout,
// 16 edges in flight. esum CSR-ordered; src-only edge list.
// ---------------------------------------------------------------------------
__global__ __launch_bounds__(256) void k_node_attn(const float* __restrict__ Q,
                                                   const float* __restrict__ KV,
                                                   const float* __restrict__ esum_csr,
                                                   const int* __restrict__ rs,
                                                   const int* __restrict__ eidxs,
                                                   float* __restrict__ wV,
                                                   float* __restrict__ z, int n) {
  const int node = (blockIdx.x * blockDim.x + threadIdx.x) >> 6;
  if (node >= n) return;
  const int lane = threadIdx.x & 63;
  const int g = lane >> 3;
  const int l = lane & 7;
  const int d0 = l << 4;
  const float* qp = Q + (size_t)node * 128 + d0;
  const float4 q0 = *(const float4*)(qp);
  const float4 q1 = *(const float4*)(qp + 4);
  const float4 q2 = *(const float4*)(qp + 8);
  const float4 q3 = *(const float4*)(qp + 12);
  float4 a0 = make_float4(0.f, 0.f, 0.f, 0.f);
  float4 a1 = a0, a2 = a0, a3 = a0;
  float zacc = 0.f;
  const int start = rs[node], end = rs[node + 1];
  for (int base = start; base < end; base += 16) {
    const bool p0 = base + g < end;
    const bool p1 = base + 8 + g < end;
    const int i0 = min(base + g, end - 1);
    const int i1 = min(base + 8 + g, end - 1);
    const int sn0 = eidxs[i0];
    const int sn1 = eidxs[i1];
    const float* kp0 = KV + (size_t)sn0 * 256 + d0;
    const float* kp1 = KV + (size_t)sn1 * 256 + d0;
    const float es0 = esum_csr[(size_t)i0 * 8 + l];
    const float es1 = esum_csr[(size_t)i1 * 8 + l];
    float4 k0, k1, k2, k3;
    k0 = *(const float4*)(kp0);
    k1 = *(const float4*)(kp0 + 4);
    k2 = *(const float4*)(kp0 + 8);
    k3 = *(const float4*)(kp0 + 12);
    float qkA = q0.x * k0.x + q0.y * k0.y + q0.z * k0.z + q0.w * k0.w
              + q1.x * k1.x + q1.y * k1.y + q1.z * k1.z + q1.w * k1.w
              + q2.x * k2.x + q2.y * k2.y + q2.z * k2.z + q2.w * k2.w
              + q3.x * k3.x + q3.y * k3.y + q3.z * k3.z + q3.w * k3.w;
    k0 = *(const float4*)(kp1);
    k1 = *(const float4*)(kp1 + 4);
    k2 = *(const float4*)(kp1 + 8);
    k3 = *(const float4*)(kp1 + 12);
    float qkB = q0.x * k0.x + q0.y * k0.y + q0.z * k0.z + q0.w * k0.w
              + q1.x * k1.x + q1.y * k1.y + q1.z * k1.z + q1.w * k1.w
              + q2.x * k2.x + q2.y * k2.y + q2.z * k2.z + q2.w * k2.w
              + q3.x * k3.x + q3.y * k3.y + q3.z * k3.z + q3.w * k3.w;
    float s0 = __expf(fminf(5.f, fmaxf(-5.f, 4.f * qkA + es0)));
    float s1 = __expf(fminf(5.f, fmaxf(-5.f, 4.f * qkB + es1)));
    s0 = p0 ? s0 : 0.f;
    s1 = p1 ? s1 : 0.f;
    {
      const float* vp = kp0 + 128;
      const float4 v0 = *(const float4*)(vp);
      const float4 v1 = *(const float4*)(vp + 4);
      const float4 v2 = *(const float4*)(vp + 8);
      const float4 v3 = *(const float4*)(vp + 12);
      a0.x += v0.x * s0; a0.y += v0.y * s0; a0.z += v0.z * s0; a0.w += v0.w * s0;
      a1.x += v1.x * s0; a1.y += v1.y * s0; a1.z += v1.z * s0; a1.w += v1.w * s0;
      a2.x += v2.x * s0; a2.y += v2.y * s0; a2.z += v2.z * s0; a2.w += v2.w * s0;
      a3.x += v3.x * s0; a3.y += v3.y * s0; a3.z += v3.z * s0; a3.w += v3.w * s0;
    }
    {
      const float* vp = kp1 + 128;
      const float4 v0 = *(const float4*)(vp);
      const float4 v1 = *(const float4*)(vp + 4);
      const float4 v2 = *(const float4*)(vp + 8);
      const float4 v3 = *(const float4*)(vp + 12);
      a0.x += v0.x * s1; a0.y += v0.y * s1; a0.z += v0.z * s1; a0.w += v0.w * s1;
      a1.x += v1.x * s1; a1.y += v1.y * s1; a1.z += v1.z * s1; a1.w += v1.w * s1;
      a2.x += v2.x * s1; a2.y += v2.y * s1; a2.z += v2.z * s1; a2.w += v2.w * s1;
      a3.x += v3.x * s1; a3.y += v3.y * s1; a3.z += v3.z * s1; a3.w += v3.w * s1;
    }
    zacc += s0 + s1;
  }
#pragma unroll
  for (int st = 8; st < 64; st <<= 1) {
    a0.x += __shfl_xor(a0.x, st); a0.y += __shfl_xor(a0.y, st);
    a0.z += __shfl_xor(a0.z, st); a0.w += __shfl_xor(a0.w, st);
    a1.x += __shfl_xor(a1.x, st); a1.y += __shfl_xor(a1.y, st);
    a1.z += __shfl_xor(a1.z, st); a1.w += __shfl_xor(a1.w, st);
    a2.x += __shfl_xor(a2.x, st); a2.y += __shfl_xor(a2.y, st);
    a2.z += __shfl_xor(a2.z, st); a2.w += __shfl_xor(a2.w, st);
    a3.x += __shfl_xor(a3.x, st); a3.y += __shfl_xor(a3.y, st);
    a3.z += __shfl_xor(a3.z, st); a3.w += __shfl_xor(a3.w, st);
    zacc += __shfl_xor(zacc, st);
  }
  if (g < 4) {
    float4 w = a0;
    if (g == 1) w = a1;
    if (g == 2) w = a2;
    if (g == 3) w = a3;
    *(float4*)(wV + (size_t)node * 128 + d0 + (g << 2)) = w;
  }
  if (g == 0) z[(size_t)node * 8 + l] = zacc;
}

// ---------------------------------------------------------------------------
// Fused: attn normalize + I@W_i + b_i -> T (LDS) -> @W_O + b_O + residual(h)
// + LN1 + BN1 -> h2. 64 rows/block, 8x4 register tiles.  (R16-exact)
// ---------------------------------------------------------------------------
__global__ __launch_bounds__(256) void k_attnln(const float* __restrict__ I_,
                                                const float* __restrict__ Wi,
                                                const float* __restrict__ bi,
                                                const float* __restrict__ wV,
                                                const float* __restrict__ z,
                                                const float* __restrict__ WO,
                                                const float* __restrict__ bO,
                                                const float* __restrict__ RES,
                                                const float* __restrict__ lng,
                                                const float* __restrict__ lnb,
                                                const float* __restrict__ bng,
                                                const float* __restrict__ bnb,
                                                float* __restrict__ Y, int n) {
  __shared__ float xs[64][132];
  __shared__ float is[64][68];
  const int t = threadIdx.x;
  const int tx = t & 31, ty = t >> 5;
  const int r0 = blockIdx.x * 64;
  const int cb = tx << 2;
  const int ty8 = ty << 3;
  for (int i = t; i < 64 * 16; i += 256) {
    const int row = i >> 4, c4 = (i & 15) << 2;
    float4 v = make_float4(0.f, 0.f, 0.f, 0.f);
    if (r0 + row < n) v = *(const float4*)(I_ + (size_t)(r0 + row) * 64 + c4);
    *(float4*)&is[row][c4] = v;
  }
  __syncthreads();
  {
    float4 acc[8];
#pragma unroll
    for (int i = 0; i < 8; ++i) acc[i] = make_float4(0.f, 0.f, 0.f, 0.f);
#pragma unroll 4
    for (int k = 0; k < 64; ++k) {
      const float4 wv = *(const float4*)(Wi + (size_t)k * 128 + cb);
#pragma unroll
      for (int i = 0; i < 8; ++i) {
        const float x = is[ty8 + i][k];
        acc[i].x += x * wv.x; acc[i].y += x * wv.y;
        acc[i].z += x * wv.z; acc[i].w += x * wv.w;
      }
    }
    const float4 bv = *(const float4*)(bi + cb);
    const int hh = cb >> 4;
#pragma unroll
    for (int i = 0; i < 8; ++i) {
      const int row = r0 + ty8 + i;
      float4 o = make_float4(0.f, 0.f, 0.f, 0.f);
      if (row < n) {
        const float rz = 1.f / (z[(size_t)row * 8 + hh] + 1e-10f);
        const float4 wv4 = *(const float4*)(wV + (size_t)row * 128 + cb);
        o.x = wv4.x * rz + acc[i].x + bv.x;
        o.y = wv4.y * rz + acc[i].y + bv.y;
        o.z = wv4.z * rz + acc[i].z + bv.z;
        o.w = wv4.w * rz + acc[i].w + bv.w;
      }
      *(float4*)&xs[ty8 + i][cb] = o;
    }
  }
  __syncthreads();
  float4 acc[8];
#pragma unroll
  for (int i = 0; i < 8; ++i) acc[i] = make_float4(0.f, 0.f, 0.f, 0.f);
#pragma unroll 4
  for (int k = 0; k < 128; ++k) {
    const float4 wv = *(const float4*)(WO + (size_t)k * 128 + cb);
#pragma unroll
    for (int i = 0; i < 8; ++i) {
      const float x = xs[ty8 + i][k];
      acc[i].x += x * wv.x; acc[i].y += x * wv.y;
      acc[i].z += x * wv.z; acc[i].w += x * wv.w;
    }
  }
  const float4 bv  = *(const float4*)(bO + cb);
  const float4 g4  = *(const float4*)(lng + cb);
  const float4 lb4 = *(const float4*)(lnb + cb);
  const float bnscale = rsqrtf(1.f + 1e-5f);
  float4 bg4 = *(const float4*)(bng + cb);
  bg4.x *= bnscale; bg4.y *= bnscale; bg4.z *= bnscale; bg4.w *= bnscale;
  const float4 bb4 = *(const float4*)(bnb + cb);
#pragma unroll
  for (int i = 0; i < 8; ++i) {
    const int row = r0 + ty8 + i;
    float4 v = acc[i];
    v.x += bv.x; v.y += bv.y; v.z += bv.z; v.w += bv.w;
    if (row < n) {
      const float4 rr = *(const float4*)(RES + (size_t)row * 128 + cb);
      v.x += rr.x; v.y += rr.y; v.z += rr.z; v.w += rr.w;
    }
    float s1 = v.x + v.y + v.z + v.w;
    float s2 = v.x * v.x + v.y * v.y + v.z * v.z + v.w * v.w;
#pragma unroll
    for (int st = 1; st < 32; st <<= 1) {
      s1 += __shfl_xor(s1, st);
      s2 += __shfl_xor(s2, st);
    }
    const float mu = s1 * (1.f / 128.f);
    const float var = s2 * (1.f / 128.f) - mu * mu;
    const float rsg = rsqrtf(var + 1e-5f);
    if (row < n) {
      float4 o;
      o.x = ((v.x - mu) * rsg * g4.x + lb4.x) * bg4.x + bb4.x;
      o.y = ((v.y - mu) * rsg * g4.y + lb4.y) * bg4.y + bb4.y;
      o.z = ((v.z - mu) * rsg * g4.z + lb4.z) * bg4.z + bb4.z;
      o.w = ((v.w - mu) * rsg * g4.w + lb4.w) * bg4.w + bb4.w;
      *(float4*)(Y + (size_t)row * 128 + cb) = o;
    }
  }
}

// ---------------------------------------------------------------------------
// 8x4 register-tiled GEMM + bias (+ReLU). (R16-exact)
// ---------------------------------------------------------------------------
template <int CI, int CO, bool RELU>
__global__ __launch_bounds__(256) void k_gemm8(const float* __restrict__ X,
                                               const float* __restrict__ W,
                                               const float* __restrict__ B,
                                               float* __restrict__ Y, int n) {
  __shared__ float xs[64][CI + 4];
  const int t = threadIdx.x;
  const int tx = t & 31, ty = t >> 5;
  const int r0 = blockIdx.x * 64;
  const int c0 = blockIdx.y * 128;
  for (int i = t; i < 64 * (CI / 4); i += 256) {
    const int row = i / (CI / 4);
    const int c4 = (i % (CI / 4)) << 2;
    float4 v = make_float4(0.f, 0.f, 0.f, 0.f);
    if (r0 + row < n) v = *(const float4*)(X + (size_t)(r0 + row) * CI + c4);
    *(float4*)&xs[row][c4] = v;
  }
  __syncthreads();
  float4 acc[8];
#pragma unroll
  for (int i = 0; i < 8; ++i) acc[i] = make_float4(0.f, 0.f, 0.f, 0.f);
  const int ty8 = ty << 3;
  const int cb = c0 + (tx << 2);
#pragma unroll 4
  for (int k = 0; k < CI; ++k) {
    const float4 wv = *(const float4*)(W + (size_t)k * CO + cb);
#pragma unroll
    for (int i = 0; i < 8; ++i) {
      const float x = xs[ty8 + i][k];
      acc[i].x += x * wv.x; acc[i].y += x * wv.y;
      acc[i].z += x * wv.z; acc[i].w += x * wv.w;
    }
  }
  const float4 bv = *(const float4*)(B + cb);
#pragma unroll
  for (int i = 0; i < 8; ++i) {
    const int row = r0 + ty8 + i;
    if (row < n) {
      float4 o;
      o.x = acc[i].x + bv.x; o.y = acc[i].y + bv.y;
      o.z = acc[i].z + bv.z; o.w = acc[i].w + bv.w;
      if (RELU) {
        o.x = fmaxf(o.x, 0.f); o.y = fmaxf(o.y, 0.f);
        o.z = fmaxf(o.z, 0.f); o.w = fmaxf(o.w, 0.f);
      }
      *(float4*)(Y + (size_t)row * CO + c0 + (tx << 2)) = o;
    }
  }
}

// ---------------------------------------------------------------------------
// 8x4 register-tiled GEMM (CI->128) + bias + residual + LN + BN. (R16-exact)
// ---------------------------------------------------------------------------
template <int CI>
__global__ __launch_bounds__(256) void k_gemm8ln(const float* __restrict__ X,
                                                 const float* __restrict__ W,
                                                 const float* __restrict__ B,
                                                 const float* __restrict__ RES,
                                                 const float* __restrict__ lng,
                                                 const float* __restrict__ lnb,
                                                 const float* __restrict__ bng,
                                                 const float* __restrict__ bnb,
                                                 float* __restrict__ Y, int n) {
  __shared__ float xs[64][132];
  const int t = threadIdx.x;
  const int tx = t & 31, ty = t >> 5;
  const int r0 = blockIdx.x * 64;
  const int cb = tx << 2;
  float4 acc[8];
#pragma unroll
  for (int i = 0; i < 8; ++i) acc[i] = make_float4(0.f, 0.f, 0.f, 0.f);
  const int ty8 = ty << 3;
  for (int kb = 0; kb < CI; kb += 128) {
    for (int i = t; i < 64 * 32; i += 256) {
      const int row = i >> 5, c4 = (i & 31) << 2;
      float4 v = make_float4(0.f, 0.f, 0.f, 0.f);
      if (r0 + row < n) v = *(const float4*)(X + (size_t)(r0 + row) * CI + kb + c4);
      *(float4*)&xs[row][c4] = v;
    }
    __syncthreads();
#pragma unroll 4
    for (int k = 0; k < 128; ++k) {
      const float4 wv = *(const float4*)(W + (size_t)(kb + k) * 128 + cb);
#pragma unroll
      for (int i = 0; i < 8; ++i) {
        const float x = xs[ty8 + i][k];
        acc[i].x += x * wv.x; acc[i].y += x * wv.y;
        acc[i].z += x * wv.z; acc[i].w += x * wv.w;
      }
    }
    __syncthreads();
  }
  const float4 bv  = *(const float4*)(B + cb);
  const float4 g4  = *(const float4*)(lng + cb);
  const float4 lb4 = *(const float4*)(lnb + cb);
  const float bnscale = rsqrtf(1.f + 1e-5f);
  float4 bg4 = *(const float4*)(bng + cb);
  bg4.x *= bnscale; bg4.y *= bnscale; bg4.z *= bnscale; bg4.w *= bnscale;
  const float4 bb4 = *(const float4*)(bnb + cb);
#pragma unroll
  for (int i = 0; i < 8; ++i) {
    const int row = r0 + ty8 + i;
    float4 v = acc[i];
    v.x += bv.x; v.y += bv.y; v.z += bv.z; v.w += bv.w;
    if (row < n) {
      const float4 rr = *(const float4*)(RES + (size_t)row * 128 + cb);
      v.x += rr.x; v.y += rr.y; v.z += rr.z; v.w += rr.w;
    }
    float s1 = v.x + v.y + v.z + v.w;
    float s2 = v.x * v.x + v.y * v.y + v.z * v.z + v.w * v.w;
#pragma unroll
    for (int st = 1; st < 32; st <<= 1) {
      s1 += __shfl_xor(s1, st);
      s2 += __shfl_xor(s2, st);
    }
    const float mu = s1 * (1.f / 128.f);
    const float var = s2 * (1.f / 128.f) - mu * mu;
    const float rsg = rsqrtf(var + 1e-5f);
    if (row < n) {
      float4 o;
      o.x = ((v.x - mu) * rsg * g4.x + lb4.x) * bg4.x + bb4.x;
      o.y = ((v.y - mu) * rsg * g4.y + lb4.y) * bg4.y + bb4.y;
      o.z = ((v.z - mu) * rsg * g4.z + lb4.z) * bg4.z + bb4.z;
      o.w = ((v.w - mu) * rsg * g4.w + lb4.w) * bg4.w + bb4.w;
      *(float4*)(Y + (size_t)row * 128 + cb) = o;
    }
  }
}

// ---------------------------------------------------------------------------
extern "C" void kernel_launch(void* const* d_in, const int* in_sizes, int n_in,
                              void* d_out, int out_size, void* d_ws, size_t ws_size,
                              hipStream_t stream) {
  const float* h_   = (const float*)d_in[0];
  const float* de   = (const float*)d_in[1];
  const float* m_   = (const float*)d_in[2];
  const float* I_   = (const float*)d_in[3];
  const float* W_Q  = (const float*)d_in[4];
  const float* b_Q  = (const float*)d_in[5];
  const float* W_K  = (const float*)d_in[6];
  const float* b_K  = (const float*)d_in[7];
  const float* W_V  = (const float*)d_in[8];
  const float* b_V  = (const float*)d_in[9];
  const float* W_pd = (const float*)d_in[10];
  const float* b_pd = (const float*)d_in[11];
  const float* W_pm = (const float*)d_in[12];
  const float* b_pm = (const float*)d_in[13];
  const float* W_i  = (const float*)d_in[14];
  const float* b_i  = (const float*)d_in[15];
  const float* W_O  = (const float*)d_in[16];
  const float* b_O  = (const float*)d_in[17];
  const float* ln1g = (const float*)d_in[18];
  const float* ln1b = (const float*)d_in[19];
  const float* bn1g = (const float*)d_in[20];
  const float* bn1b = (const float*)d_in[21];
  const float* W_f1 = (const float*)d_in[22];
  const float* b_f1 = (const float*)d_in[23];
  const float* W_f2 = (const float*)d_in[24];
  const float* b_f2 = (const float*)d_in[25];
  const float* ln2g = (const float*)d_in[26];
  const float* ln2b = (const float*)d_in[27];
  const float* bn2g = (const float*)d_in[28];
  const float* bn2b = (const float*)d_in[29];
  const int* src    = (const int*)d_in[30];
  const int* dst    = (const int*)d_in[31];

  const int N_ = in_sizes[0] / 128;   // 50000
  const int E_ = in_sizes[30];        // 800000
  const size_t ND_ = (size_t)N_ * 128;

  float* ws = (float*)d_ws;
  size_t off = 0;
  float* Qb      = ws + off; off += ND_;
  float* KVb     = ws + off; off += (size_t)N_ * 256;
  float* wV      = ws + off; off += ND_;
  float* zb      = ws + off; off += (size_t)N_ * 8;
  float* esum    = ws + off; off += (size_t)E_ * 8;
  float* esumcsr = ws + off; off += (size_t)E_ * 8;
  float* h2      = ws + off; off += ND_;
  float* hid     = ws + off; off += (size_t)N_ * 256;
  float* wpd     = ws + off; off += 1024;
  float* wpm     = ws + off; off += 1024;
  float* bs      = ws + off; off += 8;
  (void)ws_size; (void)n_in; (void)out_size;

  // CSR arrays aliased into hid (dead until FFN stage)
  int* rs     = (int*)hid;
  int* cursor = rs + (N_ + 2);
  int* eidxs  = cursor + (N_ + 2);

  float* out = (float*)d_out;
  const int nrb64 = (N_ + 63) / 64;
  const int nEsum = (E_ + 31) / 32;
  const int nQkv = 3 * nrb64;
  const int total = nEsum + nQkv;

  // 1. weight head-sums; zero counts for fused histogram
  k_wsum<<<9, 256, 0, stream>>>(W_pd, b_pd, W_pm, b_pm, wpd, wpm, bs);
  hipMemsetAsync(cursor, 0, (size_t)N_ * sizeof(int), stream);

  // 2+3. MEGA: esum (+histogram) || QKV, interleaved block roles
  k_mega<<<total, 256, 0, stream>>>(
      de, m_, wpd, wpm, bs, dst, cursor, esum, E_, nQkv, total,
      h_, W_Q, b_Q, W_K, b_K, W_V, b_V, Qb, KVb, N_);

  // 4. CSR: scan -> scatter (also permutes esum into CSR order)
  k_scan<<<1, 1024, 0, stream>>>(cursor, rs, cursor, N_);
  k_scatter2<<<1024, 256, 0, stream>>>(src, dst, cursor, (const float4*)esum,
                                       eidxs, (float4*)esumcsr, E_);

  // 5. gather-side attention
  k_node_attn<<<(N_ + 3) / 4, 256, 0, stream>>>(Qb, KVb, esumcsr, rs, eidxs, wV, zb, N_);

  // 6+7. fused: attn normalize + I@W_i -> T (LDS) -> W_O + residual + LN1 + BN1
  k_attnln<<<nrb64, 256, 0, stream>>>(I_, W_i, b_i, wV, zb, W_O, b_O, h_,
                                      ln1g, ln1b, bn1g, bn1b, h2, N_);

  // 8. FFN1 (ReLU), 8x4 tiles — overwrites CSR scratch (dead by now)
  k_gemm8<128, 256, true><<<dim3(nrb64, 2), 256, 0, stream>>>(h2, W_f1, b_f1, hid, N_);

  // 9. FFN2 + residual(h2) + LN2 + BN2 -> out (8x4 tiles, fused)
  k_gemm8ln<256><<<nrb64, 256, 0, stream>>>(hid, W_f2, b_f2, h2, ln2g, ln2b, bn2g, bn2b, out, N_);
}